// Round 3
// baseline (1492.262 us; speedup 1.0000x reference)
//
#include <hip/hip_runtime.h>
#include <hip/hip_bf16.h>
#include <stdint.h>

#define NN 10000
#define EE 50000
#define EEPAD 50176  // EE padded to multiple of 256

typedef __hip_bfloat16 bf16_t;
typedef __attribute__((ext_vector_type(8))) short bf16x8;
typedef __attribute__((ext_vector_type(4))) float f32x4;

__device__ __forceinline__ float bf2f(unsigned short u) {
  union { unsigned int i; float f; } v; v.i = ((unsigned int)u) << 16; return v.f;
}

__device__ __forceinline__ void async_load16(const void* g, void* lds) {
  __builtin_amdgcn_global_load_lds((const __attribute__((address_space(1))) uint32_t*)g,
                                   (__attribute__((address_space(3))) uint32_t*)lds,
                                   16, 0, 0);
}

#define MFMA16(a, b, c) __builtin_amdgcn_mfma_f32_16x16x32_bf16(a, b, c, 0, 0, 0)

// C[M][N] = act(A[M][K] @ Bt[N][K]^T + bias[N]); bf16 row-major; M,N mult of 256, K mult of 64 (>=128).
// 256x256 tile, BK=64, 512 threads = 8 waves (2Mx4N), per-wave 128x64 out.
// Double-buffered LDS (128 KiB), counted vmcnt(8) at K-tile boundaries, 4 quadrant phases per K-tile.
template <bool RELU>
__global__ __launch_bounds__(512, 2)
void gemm256(const bf16_t* __restrict__ A, const bf16_t* __restrict__ Bt,
             const float* __restrict__ bias, bf16_t* __restrict__ C,
             int N, int K) {
  __shared__ __align__(16) char lds[131072];
  char* LA = lds;           // A: [buf][256 rows][8 slots * 16B]
  char* LB = lds + 65536;   // B: same

  const int t = threadIdx.x;
  const int lane = t & 63;
  const int w = t >> 6;
  const int nbn = N >> 8;

  // bijective XCD swizzle (m204)
  int bid = blockIdx.x;
  {
    const int nwg = gridDim.x;
    const int q = nwg >> 3, r = nwg & 7;
    const int x = bid & 7, o = bid >> 3;
    bid = (x < r ? x * (q + 1) : r * (q + 1) + (x - r) * q) + o;
  }
  const int bm = bid / nbn, bn = bid % nbn;
  const size_t aRow0 = (size_t)bm << 8;
  const size_t bRow0 = (size_t)bn << 8;

  const int wr = w >> 2, wc = w & 3;
  const int lo = lane & 15, hi = lane >> 4;

  // fragment LDS byte offsets within a buffer (swizzled slots; r1-verified, 0 conflicts)
  int aOff[8][2], bOff[4][2];
  #pragma unroll
  for (int m = 0; m < 8; ++m) {
    const int row = (wr << 7) + (m << 4) + lo;
    #pragma unroll
    for (int ks = 0; ks < 2; ++ks)
      aOff[m][ks] = (row << 7) + ((((ks << 2) + hi) ^ (row & 7)) << 4);
  }
  #pragma unroll
  for (int n = 0; n < 4; ++n) {
    const int row = (wc << 6) + (n << 4) + lo;
    #pragma unroll
    for (int ks = 0; ks < 2; ++ks)
      bOff[n][ks] = (row << 7) + ((((ks << 2) + hi) ^ (row & 7)) << 4);
  }

  const int stg_r0 = (w << 3) + (lane >> 3);
  const int stg_s = lane & 7;

  auto stage = [&](int kt, int b) {
    char* la = LA + (b << 15);
    char* lb = LB + (b << 15);
    #pragma unroll
    for (int l = 0; l < 4; ++l) {
      const int row = stg_r0 + (l << 6);
      const int sc = ((stg_s ^ (row & 7)) << 3) + (kt << 6);  // inverse-swizzled src col
      const int dst = ((w << 3) + (l << 6)) << 7;             // wave-uniform LDS base
      async_load16(A + (aRow0 + row) * (size_t)K + sc, la + dst);
      async_load16(Bt + (bRow0 + row) * (size_t)K + sc, lb + dst);
    }
  };

  f32x4 acc[8][4] = {};
  bf16x8 af[4][2], bfv[2][2];

  const int nkt = K >> 6;
  stage(0, 0);
  stage(1, 1);
  asm volatile("s_waitcnt vmcnt(8)" ::: "memory");
  __builtin_amdgcn_s_barrier();
  asm volatile("" ::: "memory");  // fence: no LDS read hoists above the barrier

  for (int kt = 0; kt < nkt; ++kt) {
    const int b = kt & 1;
    const char* la = LA + (b << 15);
    const char* lb = LB + (b << 15);

    // Q0: af = m0-3, bfv = n0-1; MFMA m0-3 x n0-1
    #pragma unroll
    for (int m = 0; m < 4; ++m) {
      af[m][0] = *(const bf16x8*)(la + aOff[m][0]);
      af[m][1] = *(const bf16x8*)(la + aOff[m][1]);
    }
    #pragma unroll
    for (int n = 0; n < 2; ++n) {
      bfv[n][0] = *(const bf16x8*)(lb + bOff[n][0]);
      bfv[n][1] = *(const bf16x8*)(lb + bOff[n][1]);
    }
    __builtin_amdgcn_s_barrier();
    __builtin_amdgcn_s_setprio(1);
    #pragma unroll
    for (int m = 0; m < 4; ++m)
      #pragma unroll
      for (int n = 0; n < 2; ++n) {
        acc[m][n] = MFMA16(af[m][0], bfv[n][0], acc[m][n]);
        acc[m][n] = MFMA16(af[m][1], bfv[n][1], acc[m][n]);
      }
    __builtin_amdgcn_s_setprio(0);
    __builtin_amdgcn_s_barrier();

    // Q1: af = m4-7; MFMA m4-7 x n0-1
    #pragma unroll
    for (int m = 0; m < 4; ++m) {
      af[m][0] = *(const bf16x8*)(la + aOff[4 + m][0]);
      af[m][1] = *(const bf16x8*)(la + aOff[4 + m][1]);
    }
    __builtin_amdgcn_s_barrier();
    __builtin_amdgcn_s_setprio(1);
    #pragma unroll
    for (int m = 0; m < 4; ++m)
      #pragma unroll
      for (int n = 0; n < 2; ++n) {
        acc[4 + m][n] = MFMA16(af[m][0], bfv[n][0], acc[4 + m][n]);
        acc[4 + m][n] = MFMA16(af[m][1], bfv[n][1], acc[4 + m][n]);
      }
    __builtin_amdgcn_s_setprio(0);
    __builtin_amdgcn_s_barrier();

    // Q2: bfv = n2-3; MFMA m4-7 x n2-3 (af still m4-7)
    #pragma unroll
    for (int n = 0; n < 2; ++n) {
      bfv[n][0] = *(const bf16x8*)(lb + bOff[2 + n][0]);
      bfv[n][1] = *(const bf16x8*)(lb + bOff[2 + n][1]);
    }
    __builtin_amdgcn_s_barrier();
    __builtin_amdgcn_s_setprio(1);
    #pragma unroll
    for (int m = 0; m < 4; ++m)
      #pragma unroll
      for (int n = 0; n < 2; ++n) {
        acc[4 + m][2 + n] = MFMA16(af[m][0], bfv[n][0], acc[4 + m][2 + n]);
        acc[4 + m][2 + n] = MFMA16(af[m][1], bfv[n][1], acc[4 + m][2 + n]);
      }
    __builtin_amdgcn_s_setprio(0);
    __builtin_amdgcn_s_barrier();

    // Q3: af = m0-3; MFMA m0-3 x n2-3
    #pragma unroll
    for (int m = 0; m < 4; ++m) {
      af[m][0] = *(const bf16x8*)(la + aOff[m][0]);
      af[m][1] = *(const bf16x8*)(la + aOff[m][1]);
    }
    __builtin_amdgcn_s_barrier();
    __builtin_amdgcn_s_setprio(1);
    #pragma unroll
    for (int m = 0; m < 4; ++m)
      #pragma unroll
      for (int n = 0; n < 2; ++n) {
        acc[m][2 + n] = MFMA16(af[m][0], bfv[n][0], acc[m][2 + n]);
        acc[m][2 + n] = MFMA16(af[m][1], bfv[n][1], acc[m][2 + n]);
      }
    __builtin_amdgcn_s_setprio(0);
    __builtin_amdgcn_s_barrier();
    // here all waves have consumed buffer b (reads latched before their MFMAs)

    if (kt + 1 < nkt) {
      if (kt + 2 < nkt) {
        stage(kt + 2, b);  // safe: everyone is past the post-Q3 barrier
        asm volatile("s_waitcnt vmcnt(8)" ::: "memory");  // drain kt+1, keep kt+2 in flight
      } else {
        asm volatile("s_waitcnt vmcnt(0)" ::: "memory");  // nothing new issued: drain last tile
      }
      __builtin_amdgcn_s_barrier();
      asm volatile("" ::: "memory");
    }
  }

  // epilogue: C/D layout col=lane&15, row=(lane>>4)*4+j (m89-verified convention from r1)
  #pragma unroll
  for (int m = 0; m < 8; ++m) {
    #pragma unroll
    for (int n = 0; n < 4; ++n) {
      const int col = (bn << 8) + (wc << 6) + (n << 4) + lo;
      const float bv = bias[col];
      #pragma unroll
      for (int j = 0; j < 4; ++j) {
        const int row = (bm << 8) + (wr << 7) + (m << 4) + (hi << 2) + j;
        float v = acc[m][n][j] + bv;
        if (RELU) v = fmaxf(v, 0.0f);
        C[(size_t)row * N + col] = __float2bfloat16(v);
      }
    }
  }
}

// wt[n*K + k] = bf16(w[k*N + n])  (transpose + cast)
__global__ void convert_t(const float* __restrict__ w, bf16_t* __restrict__ wt,
                          int K, int N) {
  int idx = blockIdx.x * 256 + threadIdx.x;
  if (idx >= K * N) return;
  int n = idx / K, k = idx - n * K;
  wt[idx] = __float2bfloat16(w[(size_t)k * N + n]);
}

__global__ void fc1_kernel(const float* __restrict__ x, const float* __restrict__ w,
                           const float* __restrict__ b, float* __restrict__ h) {
  int idx = blockIdx.x * 256 + threadIdx.x;
  if (idx >= NN * 64) return;
  int n = idx >> 6, j = idx & 63;
  h[idx] = fmaf(x[n], w[j], b[j]);
}

__global__ void deg_kernel(const int* __restrict__ ei, float* __restrict__ deg) {
  int e = blockIdx.x * 256 + threadIdx.x;
  if (e < EE) {
    unsigned d = (unsigned)ei[EE + e];
    if (d < NN) atomicAdd(&deg[d], 1.0f);
  }
}

// e1[el][0:256] = relu(attr[e0+el] @ k1_w + k1_b), zeros for rows >= ne
__global__ void k1_kernel(const float* __restrict__ attr, const float* __restrict__ w,
                          const float* __restrict__ b, bf16_t* __restrict__ e1,
                          int e0, int ne) {
  const int el = blockIdx.x;
  const int j = threadIdx.x;
  __shared__ float a[6];
  if (el < ne && j < 6) a[j] = attr[(size_t)(e0 + el) * 6 + j];
  __syncthreads();
  float v = 0.0f;
  if (el < ne) {
    v = b[j];
    #pragma unroll
    for (int i = 0; i < 6; ++i) v = fmaf(a[i], w[i * 256 + j], v);
    v = fmaxf(v, 0.0f);
  }
  e1[(size_t)el * 256 + j] = __float2bfloat16(v);
}

// per-edge matvec msg[o] = sum_i h[src][i] * W[el][i*64+o], atomic scatter to agg[dst]
__global__ __launch_bounds__(256)
void msg_kernel(const float* __restrict__ h, const bf16_t* __restrict__ W,
                const int* __restrict__ ei, float* __restrict__ agg,
                int e0, int ne) {
  const int el = blockIdx.x * 4 + (threadIdx.x >> 6);
  if (el >= ne) return;
  const int e = e0 + el;
  const int lane = threadIdx.x & 63;
  const int g = lane >> 4, c = lane & 15;
  const unsigned src = (unsigned)ei[e], dst = (unsigned)ei[EE + e];
  if (src >= NN || dst >= NN) return;
  const float hv = h[src * 64 + lane];
  const unsigned short* We = (const unsigned short*)(W + (size_t)el * 4096);
  float a0 = 0, a1 = 0, a2 = 0, a3 = 0;
  #pragma unroll
  for (int i0 = 0; i0 < 64; i0 += 4) {
    const int i = i0 + g;
    const float hs = __shfl(hv, i);
    ushort4 wv = *(const ushort4*)(We + i * 64 + c * 4);
    a0 = fmaf(hs, bf2f(wv.x), a0);
    a1 = fmaf(hs, bf2f(wv.y), a1);
    a2 = fmaf(hs, bf2f(wv.z), a2);
    a3 = fmaf(hs, bf2f(wv.w), a3);
  }
  a0 += __shfl_xor(a0, 16); a0 += __shfl_xor(a0, 32);
  a1 += __shfl_xor(a1, 16); a1 += __shfl_xor(a1, 32);
  a2 += __shfl_xor(a2, 16); a2 += __shfl_xor(a2, 32);
  a3 += __shfl_xor(a3, 16); a3 += __shfl_xor(a3, 32);
  if (g == 0) {
    float* ag = agg + (size_t)dst * 64 + c * 4;
    atomicAdd(ag + 0, a0);
    atomicAdd(ag + 1, a1);
    atomicAdd(ag + 2, a2);
    atomicAdd(ag + 3, a3);
  }
}

// h_new = relu(agg/deg + h @ root + gcn_b)
__global__ __launch_bounds__(256)
void update_kernel(const float* __restrict__ h, const float* __restrict__ agg,
                   const float* __restrict__ deg, const float* __restrict__ root,
                   const float* __restrict__ gb, float* __restrict__ hn) {
  const int n = blockIdx.x * 4 + (threadIdx.x >> 6);
  if (n >= NN) return;
  const int lane = threadIdx.x & 63;
  const float hv = h[n * 64 + lane];
  float acc = 0.0f;
  #pragma unroll
  for (int i = 0; i < 64; ++i)
    acc = fmaf(__shfl(hv, i), root[i * 64 + lane], acc);
  const float d = fmaxf(deg[n], 1.0f);
  const float v = agg[n * 64 + lane] / d + acc + gb[lane];
  hn[n * 64 + lane] = fmaxf(v, 0.0f);
}

__global__ __launch_bounds__(256)
void fc2_kernel(const float* __restrict__ h, const float* __restrict__ w,
                const float* __restrict__ b, float* __restrict__ out) {
  const int n = blockIdx.x * 4 + (threadIdx.x >> 6);
  if (n >= NN) return;
  const int lane = threadIdx.x & 63;
  float v = h[n * 64 + lane] * w[lane];
  #pragma unroll
  for (int off = 32; off > 0; off >>= 1) v += __shfl_xor(v, off);
  if (lane == 0) out[n] = v + b[0];
}

extern "C" void kernel_launch(void* const* d_in, const int* in_sizes, int n_in,
                              void* d_out, int out_size, void* d_ws, size_t ws_size,
                              hipStream_t stream) {
  const float* x     = (const float*)d_in[0];
  const int*   ei    = (const int*)d_in[1];
  const float* attr  = (const float*)d_in[2];
  const float* fc1_w = (const float*)d_in[3];
  const float* fc1_b = (const float*)d_in[4];
  const float* k1_w  = (const float*)d_in[5];
  const float* k1_b  = (const float*)d_in[6];
  const float* k2_w  = (const float*)d_in[7];
  const float* k2_b  = (const float*)d_in[8];
  const float* k3_w  = (const float*)d_in[9];
  const float* k3_b  = (const float*)d_in[10];
  const float* root  = (const float*)d_in[11];
  const float* gcn_b = (const float*)d_in[12];
  const float* fc2_w = (const float*)d_in[13];
  const float* fc2_b = (const float*)d_in[14];
  float* out = (float*)d_out;
  (void)in_sizes; (void)n_in; (void)out_size;

  char* ws = (char*)d_ws;
  size_t off = 0;
  auto take = [&](size_t bytes) -> char* {
    char* p = ws + off;
    off += (bytes + 255) & ~(size_t)255;
    return p;
  };
  // fixed small buffers (~12.4 MB)
  bf16_t* k2wt = (bf16_t*)take((size_t)512 * 256 * 2);
  bf16_t* k3wt = (bf16_t*)take((size_t)4096 * 512 * 2);
  float*  hA   = (float*)take((size_t)NN * 64 * 4);
  float*  hB   = (float*)take((size_t)NN * 64 * 4);
  float*  agg  = (float*)take((size_t)NN * 64 * 4);
  float*  deg  = (float*)take((size_t)NN * 4);

  // recompute chunk (multiple of 256) + W cache sized from remaining ws
  int Cc = 6400;
  size_t chunkBytes = (size_t)Cc * (512 + 1024 + 8192) + 1024;
  if (ws_size < off + chunkBytes + 4096) { Cc = 2560; chunkBytes = (size_t)Cc * 9728 + 1024; }
  size_t avail = (ws_size > off + chunkBytes + 4096) ? (ws_size - off - chunkBytes - 4096) : 0;
  long nc = (long)(avail / 8192);
  int Nc = (int)(nc / 256) * 256;
  if (Nc > EEPAD) Nc = EEPAD;
  if (Nc < 0) Nc = 0;
  bf16_t* Wcache = (bf16_t*)take((size_t)Nc * 4096 * 2);
  bf16_t* e1   = (bf16_t*)take((size_t)Cc * 256 * 2);
  bf16_t* e2   = (bf16_t*)take((size_t)Cc * 512 * 2);
  bf16_t* Wtmp = (bf16_t*)take((size_t)Cc * 4096 * 2);

  const int NcE = (Nc < EE) ? Nc : EE;  // cached real edges

  // weight transposes + casts
  convert_t<<<(512 * 256 + 255) / 256, 256, 0, stream>>>(k2_w, k2wt, 256, 512);
  convert_t<<<(4096 * 512 + 255) / 256, 256, 0, stream>>>(k3_w, k3wt, 512, 4096);

  // h0 = x @ fc1_w + fc1_b
  fc1_kernel<<<(NN * 64 + 255) / 256, 256, 0, stream>>>(x, fc1_w, fc1_b, hA);

  // in-degree
  hipMemsetAsync(deg, 0, NN * 4, stream);
  deg_kernel<<<(EE + 255) / 256, 256, 0, stream>>>(ei, deg);

  // one edge-MLP chunk: k1 -> k2 -> k3 (into Wdst), then msg
  auto edge_chunk = [&](const float* hc, int e0, int ne, bf16_t* Wdst) {
    const int np = (ne + 255) & ~255;
    k1_kernel<<<np, 256, 0, stream>>>(attr, k1_w, k1_b, e1, e0, ne);
    gemm256<true><<<(np >> 8) * 2, 512, 0, stream>>>(e1, k2wt, k2_b, e2, 512, 256);
    gemm256<false><<<(np >> 8) * 16, 512, 0, stream>>>(e2, k3wt, k3_b, Wdst, 4096, 512);
    msg_kernel<<<(ne + 3) / 4, 256, 0, stream>>>(hc, Wdst, ei, agg, e0, ne);
  };

  float* hc = hA;
  float* hn = hB;
  for (int l = 0; l < 3; ++l) {
    hipMemsetAsync(agg, 0, (size_t)NN * 64 * 4, stream);
    if (l == 0) {
      // fill cache while doing layer-0 msg
      for (int c = 0; c < NcE; c += Cc) {
        int ne = NcE - c; if (ne > Cc) ne = Cc;
        edge_chunk(hc, c, ne, Wcache + (size_t)c * 4096);
      }
    } else if (NcE > 0) {
      msg_kernel<<<(NcE + 3) / 4, 256, 0, stream>>>(hc, Wcache, ei, agg, 0, NcE);
    }
    // tail: recompute each layer
    for (int c = NcE; c < EE; c += Cc) {
      int ne = EE - c; if (ne > Cc) ne = Cc;
      edge_chunk(hc, c, ne, Wtmp);
    }
    update_kernel<<<(NN + 3) / 4, 256, 0, stream>>>(hc, agg, deg, root, gcn_b, hn);
    float* tmp = hc; hc = hn; hn = tmp;
  }

  fc2_kernel<<<(NN + 3) / 4, 256, 0, stream>>>(hc, fc2_w, fc2_b, out);
}

// Round 4
// 1101.015 us; speedup vs baseline: 1.3554x; 1.3554x over previous
//
#include <hip/hip_runtime.h>
#include <hip/hip_bf16.h>
#include <stdint.h>

#define NN 10000
#define EE 50000
#define EEPAD 50176  // EE padded to multiple of 256

typedef __hip_bfloat16 bf16_t;
typedef __attribute__((ext_vector_type(8))) short bf16x8;
typedef __attribute__((ext_vector_type(4))) float f32x4;

__device__ __forceinline__ float bf2f(unsigned short u) {
  union { unsigned int i; float f; } v; v.i = ((unsigned int)u) << 16; return v.f;
}

__device__ __forceinline__ void async_load16(const void* g, void* lds) {
  __builtin_amdgcn_global_load_lds((const __attribute__((address_space(1))) uint32_t*)g,
                                   (__attribute__((address_space(3))) uint32_t*)lds,
                                   16, 0, 0);
}

// C[M][N] = act(A[M][K] @ Bt[N][K]^T + bias[N]); A,Bt,C bf16 row-major, M mult 128, N mult 128, K mult 64.
// 128x128 tile, BK=64, 256 threads = 4 waves (2x2), each wave 64x64 (4x4 fragments of 16x16x32).
// Proven r2 structure: 944 TF, MfmaUtil 42%, 0 bank conflicts. DO NOT TOUCH without A/B.
template <bool RELU>
__global__ __launch_bounds__(256, 2)
void gemm_bt(const bf16_t* __restrict__ A, const bf16_t* __restrict__ Bt,
             const float* __restrict__ bias, bf16_t* __restrict__ C,
             int N, int K) {
  __shared__ __align__(16) bf16_t As[128 * 64];
  __shared__ __align__(16) bf16_t Bs[128 * 64];

  const int t = threadIdx.x;
  const int lane = t & 63;
  const int wave = t >> 6;
  const int nt = N >> 7;
  const int bm = blockIdx.x / nt;
  const int bn = blockIdx.x % nt;
  const size_t aRowBase = (size_t)bm << 7;
  const size_t bRowBase = (size_t)bn << 7;

  const int wrBase = (wave >> 1) << 6;
  const int wcBase = (wave & 1) << 6;
  const int lo = lane & 15;
  const int hi = lane >> 4;

  f32x4 acc[4][4] = {};

  const int stg_r = t >> 3;   // row within 32-row issue chunk
  const int stg_s = t & 7;    // 16B slot within 128B row
  char* AsB = (char*)As;
  char* BsB = (char*)Bs;

  const int nkt = K >> 6;
  for (int kt = 0; kt < nkt; ++kt) {
    __syncthreads();
    #pragma unroll
    for (int it = 0; it < 4; ++it) {
      const int r = (it << 5) + stg_r;
      const int ls = (stg_s ^ (r & 7)) << 3;  // inverse-swizzled source element offset
      async_load16(A + (aRowBase + r) * K + (kt << 6) + ls,
                   AsB + (it << 12) + (wave << 10));
      async_load16(Bt + (bRowBase + r) * K + (kt << 6) + ls,
                   BsB + (it << 12) + (wave << 10));
    }
    __syncthreads();
    #pragma unroll
    for (int ks = 0; ks < 2; ++ks) {
      bf16x8 af[4], bfr[4];
      #pragma unroll
      for (int m = 0; m < 4; ++m) {
        const int row = wrBase + (m << 4) + lo;
        const int ps = ((ks << 2) + hi) ^ (row & 7);  // swizzled read slot
        af[m] = *(const bf16x8*)(AsB + (row << 7) + (ps << 4));
      }
      #pragma unroll
      for (int n = 0; n < 4; ++n) {
        const int row = wcBase + (n << 4) + lo;
        const int ps = ((ks << 2) + hi) ^ (row & 7);
        bfr[n] = *(const bf16x8*)(BsB + (row << 7) + (ps << 4));
      }
      #pragma unroll
      for (int m = 0; m < 4; ++m)
        #pragma unroll
        for (int n = 0; n < 4; ++n)
          acc[m][n] = __builtin_amdgcn_mfma_f32_16x16x32_bf16(af[m], bfr[n], acc[m][n], 0, 0, 0);
    }
  }

  // epilogue: C/D layout col=lane&15, row=(lane>>4)*4+j (m89-verified)
  #pragma unroll
  for (int m = 0; m < 4; ++m) {
    #pragma unroll
    for (int n = 0; n < 4; ++n) {
      const int col = (bn << 7) + wcBase + (n << 4) + lo;
      const float bv = bias[col];
      #pragma unroll
      for (int j = 0; j < 4; ++j) {
        const int row = (bm << 7) + wrBase + (m << 4) + (hi << 2) + j;
        float v = acc[m][n][j] + bv;
        if (RELU) v = fmaxf(v, 0.0f);
        C[(size_t)row * N + col] = __float2bfloat16(v);
      }
    }
  }
}

// wt[n*K + k] = bf16(w[k*N + n])  (transpose + cast)
__global__ void convert_t(const float* __restrict__ w, bf16_t* __restrict__ wt,
                          int K, int N) {
  int idx = blockIdx.x * 256 + threadIdx.x;
  if (idx >= K * N) return;
  int n = idx / K, k = idx - n * K;
  wt[idx] = __float2bfloat16(w[(size_t)k * N + n]);
}

__global__ void fc1_kernel(const float* __restrict__ x, const float* __restrict__ w,
                           const float* __restrict__ b, float* __restrict__ h) {
  int idx = blockIdx.x * 256 + threadIdx.x;
  if (idx >= NN * 64) return;
  int n = idx >> 6, j = idx & 63;
  h[idx] = fmaf(x[n], w[j], b[j]);
}

__global__ void deg_kernel(const int* __restrict__ ei, float* __restrict__ deg) {
  int e = blockIdx.x * 256 + threadIdx.x;
  if (e < EE) {
    unsigned d = (unsigned)ei[EE + e];
    if (d < NN) atomicAdd(&deg[d], 1.0f);
  }
}

// e1[el][0:256] = relu(attr[e0+el] @ k1_w + k1_b), zeros for rows >= ne
__global__ void k1_kernel(const float* __restrict__ attr, const float* __restrict__ w,
                          const float* __restrict__ b, bf16_t* __restrict__ e1,
                          int e0, int ne) {
  const int el = blockIdx.x;
  const int j = threadIdx.x;
  __shared__ float a[6];
  if (el < ne && j < 6) a[j] = attr[(size_t)(e0 + el) * 6 + j];
  __syncthreads();
  float v = 0.0f;
  if (el < ne) {
    v = b[j];
    #pragma unroll
    for (int i = 0; i < 6; ++i) v = fmaf(a[i], w[i * 256 + j], v);
    v = fmaxf(v, 0.0f);
  }
  e1[(size_t)el * 256 + j] = __float2bfloat16(v);
}

// per-edge matvec msg[o] = sum_i h[src][i] * W[el][i*64+o], atomic scatter to agg[dst]
__global__ __launch_bounds__(256)
void msg_kernel(const float* __restrict__ h, const bf16_t* __restrict__ W,
                const int* __restrict__ ei, float* __restrict__ agg,
                int e0, int ne) {
  const int el = blockIdx.x * 4 + (threadIdx.x >> 6);
  if (el >= ne) return;
  const int e = e0 + el;
  const int lane = threadIdx.x & 63;
  const int g = lane >> 4, c = lane & 15;
  const unsigned src = (unsigned)ei[e], dst = (unsigned)ei[EE + e];
  if (src >= NN || dst >= NN) return;
  const float hv = h[src * 64 + lane];
  const unsigned short* We = (const unsigned short*)(W + (size_t)el * 4096);
  float a0 = 0, a1 = 0, a2 = 0, a3 = 0;
  #pragma unroll
  for (int i0 = 0; i0 < 64; i0 += 4) {
    const int i = i0 + g;
    const float hs = __shfl(hv, i);
    ushort4 wv = *(const ushort4*)(We + i * 64 + c * 4);
    a0 = fmaf(hs, bf2f(wv.x), a0);
    a1 = fmaf(hs, bf2f(wv.y), a1);
    a2 = fmaf(hs, bf2f(wv.z), a2);
    a3 = fmaf(hs, bf2f(wv.w), a3);
  }
  a0 += __shfl_xor(a0, 16); a0 += __shfl_xor(a0, 32);
  a1 += __shfl_xor(a1, 16); a1 += __shfl_xor(a1, 32);
  a2 += __shfl_xor(a2, 16); a2 += __shfl_xor(a2, 32);
  a3 += __shfl_xor(a3, 16); a3 += __shfl_xor(a3, 32);
  if (g == 0) {
    float* ag = agg + (size_t)dst * 64 + c * 4;
    atomicAdd(ag + 0, a0);
    atomicAdd(ag + 1, a1);
    atomicAdd(ag + 2, a2);
    atomicAdd(ag + 3, a3);
  }
}

// h_new = relu(agg/deg + h @ root + gcn_b)
__global__ __launch_bounds__(256)
void update_kernel(const float* __restrict__ h, const float* __restrict__ agg,
                   const float* __restrict__ deg, const float* __restrict__ root,
                   const float* __restrict__ gb, float* __restrict__ hn) {
  const int n = blockIdx.x * 4 + (threadIdx.x >> 6);
  if (n >= NN) return;
  const int lane = threadIdx.x & 63;
  const float hv = h[n * 64 + lane];
  float acc = 0.0f;
  #pragma unroll
  for (int i = 0; i < 64; ++i)
    acc = fmaf(__shfl(hv, i), root[i * 64 + lane], acc);
  const float d = fmaxf(deg[n], 1.0f);
  const float v = agg[n * 64 + lane] / d + acc + gb[lane];
  hn[n * 64 + lane] = fmaxf(v, 0.0f);
}

__global__ __launch_bounds__(256)
void fc2_kernel(const float* __restrict__ h, const float* __restrict__ w,
                const float* __restrict__ b, float* __restrict__ out) {
  const int n = blockIdx.x * 4 + (threadIdx.x >> 6);
  if (n >= NN) return;
  const int lane = threadIdx.x & 63;
  float v = h[n * 64 + lane] * w[lane];
  #pragma unroll
  for (int off = 32; off > 0; off >>= 1) v += __shfl_xor(v, off);
  if (lane == 0) out[n] = v + b[0];
}

extern "C" void kernel_launch(void* const* d_in, const int* in_sizes, int n_in,
                              void* d_out, int out_size, void* d_ws, size_t ws_size,
                              hipStream_t stream) {
  const float* x     = (const float*)d_in[0];
  const int*   ei    = (const int*)d_in[1];
  const float* attr  = (const float*)d_in[2];
  const float* fc1_w = (const float*)d_in[3];
  const float* fc1_b = (const float*)d_in[4];
  const float* k1_w  = (const float*)d_in[5];
  const float* k1_b  = (const float*)d_in[6];
  const float* k2_w  = (const float*)d_in[7];
  const float* k2_b  = (const float*)d_in[8];
  const float* k3_w  = (const float*)d_in[9];
  const float* k3_b  = (const float*)d_in[10];
  const float* root  = (const float*)d_in[11];
  const float* gcn_b = (const float*)d_in[12];
  const float* fc2_w = (const float*)d_in[13];
  const float* fc2_b = (const float*)d_in[14];
  float* out = (float*)d_out;
  (void)in_sizes; (void)n_in; (void)out_size;

  char* ws = (char*)d_ws;
  size_t off = 0;
  auto take = [&](size_t bytes) -> char* {
    char* p = ws + off;
    off += (bytes + 255) & ~(size_t)255;
    return p;
  };
  // fixed small buffers (~12.2 MB)
  bf16_t* k2wt = (bf16_t*)take((size_t)512 * 256 * 2);
  bf16_t* k3wt = (bf16_t*)take((size_t)4096 * 512 * 2);
  float*  hA   = (float*)take((size_t)NN * 64 * 4);
  float*  hB   = (float*)take((size_t)NN * 64 * 4);
  float*  agg  = (float*)take((size_t)NN * 64 * 4);
  float*  deg  = (float*)take((size_t)NN * 4);

  // chunk scratch (e1 + e2 + Wtmp = 9728 B/edge) sized first, W cache gets the rest.
  // At ws=256MiB: Cc=6144 (scratch 59.8MB), Nc=23808 (cache 195MB).
  size_t avail = (ws_size > off + 4096) ? (ws_size - off - 4096) : 0;
  int Cc = 6144;
  while (Cc > 768 && (size_t)Cc * 9728 + 1024 > avail) Cc >>= 1;
  size_t scratch = (size_t)Cc * 9728 + 1024;
  long ncl = (avail > scratch) ? (long)((avail - scratch) / 8192) : 0;
  int Nc = (int)(ncl / 256) * 256;
  if (Nc > EEPAD) Nc = EEPAD;
  if (Nc < 0) Nc = 0;
  bf16_t* Wcache = (bf16_t*)take((size_t)Nc * 4096 * 2);
  bf16_t* e1   = (bf16_t*)take((size_t)Cc * 256 * 2);
  bf16_t* e2   = (bf16_t*)take((size_t)Cc * 512 * 2);
  bf16_t* Wtmp = (bf16_t*)take((size_t)Cc * 4096 * 2);

  const int NcE = (Nc < EE) ? Nc : EE;  // cached real edges

  // weight transposes + casts
  convert_t<<<(512 * 256 + 255) / 256, 256, 0, stream>>>(k2_w, k2wt, 256, 512);
  convert_t<<<(4096 * 512 + 255) / 256, 256, 0, stream>>>(k3_w, k3wt, 512, 4096);

  // h0 = x @ fc1_w + fc1_b
  fc1_kernel<<<(NN * 64 + 255) / 256, 256, 0, stream>>>(x, fc1_w, fc1_b, hA);

  // in-degree
  hipMemsetAsync(deg, 0, NN * 4, stream);
  deg_kernel<<<(EE + 255) / 256, 256, 0, stream>>>(ei, deg);

  // one edge-MLP chunk: k1 -> k2 -> k3 (into Wdst), then msg for those edges
  auto edge_chunk = [&](const float* hc, int e0, int ne, bf16_t* Wdst) {
    const int np = (ne + 127) & ~127;
    k1_kernel<<<np, 256, 0, stream>>>(attr, k1_w, k1_b, e1, e0, ne);
    gemm_bt<true><<<(np >> 7) * 4, 256, 0, stream>>>(e1, k2wt, k2_b, e2, 512, 256);
    gemm_bt<false><<<(np >> 7) * 32, 256, 0, stream>>>(e2, k3wt, k3_b, Wdst, 4096, 512);
    msg_kernel<<<(ne + 3) / 4, 256, 0, stream>>>(hc, Wdst, ei, agg, e0, ne);
  };

  float* hc = hA;
  float* hn = hB;
  for (int l = 0; l < 3; ++l) {
    hipMemsetAsync(agg, 0, (size_t)NN * 64 * 4, stream);
    if (l == 0) {
      // layer 0: fill cache chunk-by-chunk (msg included)
      for (int c = 0; c < NcE; c += Cc) {
        int ne = NcE - c; if (ne > Cc) ne = Cc;
        edge_chunk(hc, c, ne, Wcache + (size_t)c * 4096);
      }
    } else if (NcE > 0) {
      // layers 1-2: cached part is one big msg dispatch
      msg_kernel<<<(NcE + 3) / 4, 256, 0, stream>>>(hc, Wcache, ei, agg, 0, NcE);
    }
    // tail: recompute every layer
    for (int c = NcE; c < EE; c += Cc) {
      int ne = EE - c; if (ne > Cc) ne = Cc;
      edge_chunk(hc, c, ne, Wtmp);
    }
    update_kernel<<<(NN + 3) / 4, 256, 0, stream>>>(hc, agg, deg, root, gcn_b, hn);
    float* tmp = hc; hc = hn; hn = tmp;
  }

  fc2_kernel<<<(NN + 3) / 4, 256, 0, stream>>>(hc, fc2_w, fc2_b, out);
}

// Round 5
// 904.330 us; speedup vs baseline: 1.6501x; 1.2175x over previous
//
#include <hip/hip_runtime.h>
#include <hip/hip_bf16.h>
#include <stdint.h>

#define NN 10000
#define EE 50000
#define MPAD 50176  // EE padded to multiple of 128 used for e1/e2 buffers

typedef __hip_bfloat16 bf16_t;
typedef __attribute__((ext_vector_type(8))) short bf16x8;
typedef __attribute__((ext_vector_type(4))) float f32x4;

__device__ __forceinline__ float bf2f(unsigned short u) {
  union { unsigned int i; float f; } v; v.i = ((unsigned int)u) << 16; return v.f;
}

__device__ __forceinline__ void async_load16(const void* g, void* lds) {
  __builtin_amdgcn_global_load_lds((const __attribute__((address_space(1))) uint32_t*)g,
                                   (__attribute__((address_space(3))) uint32_t*)lds,
                                   16, 0, 0);
}

#define MFMA16(a, b, c) __builtin_amdgcn_mfma_f32_16x16x32_bf16(a, b, c, 0, 0, 0)

// C[M][N] = act(A[M][K] @ Bt[N][K]^T + bias[N]); bf16 row-major, M,N mult 128, K mult 64.
// Proven r2 structure: 944 TF, MfmaUtil 42%, 0 bank conflicts. DO NOT TOUCH without A/B.
template <bool RELU>
__global__ __launch_bounds__(256, 2)
void gemm_bt(const bf16_t* __restrict__ A, const bf16_t* __restrict__ Bt,
             const float* __restrict__ bias, bf16_t* __restrict__ C,
             int N, int K) {
  __shared__ __align__(16) bf16_t As[128 * 64];
  __shared__ __align__(16) bf16_t Bs[128 * 64];

  const int t = threadIdx.x;
  const int lane = t & 63;
  const int wave = t >> 6;
  const int nt = N >> 7;
  const int bm = blockIdx.x / nt;
  const int bn = blockIdx.x % nt;
  const size_t aRowBase = (size_t)bm << 7;
  const size_t bRowBase = (size_t)bn << 7;

  const int wrBase = (wave >> 1) << 6;
  const int wcBase = (wave & 1) << 6;
  const int lo = lane & 15;
  const int hi = lane >> 4;

  f32x4 acc[4][4] = {};

  const int stg_r = t >> 3;
  const int stg_s = t & 7;
  char* AsB = (char*)As;
  char* BsB = (char*)Bs;

  const int nkt = K >> 6;
  for (int kt = 0; kt < nkt; ++kt) {
    __syncthreads();
    #pragma unroll
    for (int it = 0; it < 4; ++it) {
      const int r = (it << 5) + stg_r;
      const int ls = (stg_s ^ (r & 7)) << 3;
      async_load16(A + (aRowBase + r) * K + (kt << 6) + ls,
                   AsB + (it << 12) + (wave << 10));
      async_load16(Bt + (bRowBase + r) * K + (kt << 6) + ls,
                   BsB + (it << 12) + (wave << 10));
    }
    __syncthreads();
    #pragma unroll
    for (int ks = 0; ks < 2; ++ks) {
      bf16x8 af[4], bfr[4];
      #pragma unroll
      for (int m = 0; m < 4; ++m) {
        const int row = wrBase + (m << 4) + lo;
        const int ps = ((ks << 2) + hi) ^ (row & 7);
        af[m] = *(const bf16x8*)(AsB + (row << 7) + (ps << 4));
      }
      #pragma unroll
      for (int n = 0; n < 4; ++n) {
        const int row = wcBase + (n << 4) + lo;
        const int ps = ((ks << 2) + hi) ^ (row & 7);
        bfr[n] = *(const bf16x8*)(BsB + (row << 7) + (ps << 4));
      }
      #pragma unroll
      for (int m = 0; m < 4; ++m)
        #pragma unroll
        for (int n = 0; n < 4; ++n)
          acc[m][n] = MFMA16(af[m], bfr[n], acc[m][n]);
    }
  }

  #pragma unroll
  for (int m = 0; m < 4; ++m) {
    #pragma unroll
    for (int n = 0; n < 4; ++n) {
      const int col = (bn << 7) + wcBase + (n << 4) + lo;
      const float bv = bias[col];
      #pragma unroll
      for (int j = 0; j < 4; ++j) {
        const int row = (bm << 7) + wrBase + (m << 4) + (hi << 2) + j;
        float v = acc[m][n][j] + bv;
        if (RELU) v = fmaxf(v, 0.0f);
        C[(size_t)row * N + col] = __float2bfloat16(v);
      }
    }
  }
}

// Fused k3 GEMM + per-edge matvec + scatter.
// A = e2 rows (dispatch-local), Bt = k3wt [4096][512], b3 = k3_b.
// Each block: 128 edge-rows, bn-tiles bn = s+4*bi (bi=0..7), K=512.
// Per bn: C_tile = A@Bt + b3 (cols i*64+o, i=2bn+i2); fold msg[r,o] += h[src_r,i]*C.
// End: atomicAdd agg[dst_r*64+o]. WW: also write C (bf16) to Wout[row][4096].
// Wave tiling: 4 waves x 32 rows, each wave full 128 cols -> complete (row,o) in-wave.
template <bool WW>
__global__ __launch_bounds__(256, 2)
void k3msg(const bf16_t* __restrict__ A, const bf16_t* __restrict__ Bt,
           const float* __restrict__ b3, const float* __restrict__ h,
           const int* __restrict__ ei, float* __restrict__ agg,
           bf16_t* __restrict__ Wout, int e0, int ne) {
  __shared__ __align__(16) bf16_t As[128 * 64];
  __shared__ __align__(16) bf16_t Bs[128 * 64];
  char* AsB = (char*)As;
  char* BsB = (char*)Bs;

  const int t = threadIdx.x, lane = t & 63, w = t >> 6;
  const int mt = blockIdx.x >> 2;   // M-tile
  const int s = blockIdx.x & 3;     // bn split (SPLIT=4)
  const int lo = lane & 15, hi = lane >> 4;
  const int aRow0 = mt << 7;

  // per-lane edge rows: rloc = w*32 + m*16 + hi*4 + j
  int srcr[2][4], dstr[2][4], rga[2][4];
  bool val[2][4];
  #pragma unroll
  for (int m = 0; m < 2; ++m) {
    #pragma unroll
    for (int j = 0; j < 4; ++j) {
      const int rloc = (w << 5) + (m << 4) + (hi << 2) + j;
      const int rg = aRow0 + rloc;
      rga[m][j] = rg;
      bool v = (rg < ne);
      unsigned sv = 0u, dv = 0u;
      if (v) {
        const int eg = e0 + rg;
        sv = (unsigned)ei[eg];
        dv = (unsigned)ei[EE + eg];
        if (sv >= NN || dv >= NN) v = false;
      }
      srcr[m][j] = (int)sv; dstr[m][j] = (int)dv; val[m][j] = v;
    }
  }

  const int stg_r = t >> 3;
  const int stg_s = t & 7;

  float msg[2][4][4] = {};  // [m][na][j], o = na*16+lo

  for (int bi = 0; bi < 8; ++bi) {
    const int bn = s + (bi << 2);
    f32x4 acc[2][8] = {};
    for (int kt = 0; kt < 8; ++kt) {  // K = 512
      __syncthreads();
      #pragma unroll
      for (int it = 0; it < 4; ++it) {
        const int r = (it << 5) + stg_r;
        const int ls = (stg_s ^ (r & 7)) << 3;
        async_load16(A + (size_t)(aRow0 + r) * 512 + (kt << 6) + ls,
                     AsB + (it << 12) + (w << 10));
        async_load16(Bt + (size_t)((bn << 7) + r) * 512 + (kt << 6) + ls,
                     BsB + (it << 12) + (w << 10));
      }
      __syncthreads();
      #pragma unroll
      for (int ks = 0; ks < 2; ++ks) {
        bf16x8 af[2], bfr[8];
        #pragma unroll
        for (int m = 0; m < 2; ++m) {
          const int row = (w << 5) + (m << 4) + lo;
          const int ps = ((ks << 2) + hi) ^ (row & 7);
          af[m] = *(const bf16x8*)(AsB + (row << 7) + (ps << 4));
        }
        #pragma unroll
        for (int n = 0; n < 8; ++n) {
          const int row = (n << 4) + lo;
          const int ps = ((ks << 2) + hi) ^ (row & 7);
          bfr[n] = *(const bf16x8*)(BsB + (row << 7) + (ps << 4));
        }
        #pragma unroll
        for (int m = 0; m < 2; ++m)
          #pragma unroll
          for (int n = 0; n < 8; ++n)
            acc[m][n] = MFMA16(af[m], bfr[n], acc[m][n]);
      }
    }
    // fold this bn's C-tile into msg (registers only, no LDS)
    float hsc[2][4][2];
    #pragma unroll
    for (int m = 0; m < 2; ++m) {
      #pragma unroll
      for (int j = 0; j < 4; ++j) {
        const size_t hb = (size_t)srcr[m][j] * 64 + (bn << 1);
        hsc[m][j][0] = val[m][j] ? h[hb] : 0.0f;
        hsc[m][j][1] = val[m][j] ? h[hb + 1] : 0.0f;
      }
    }
    #pragma unroll
    for (int n = 0; n < 8; ++n) {
      const int col = (bn << 7) + (n << 4) + lo;
      const float bv = b3[col];
      #pragma unroll
      for (int m = 0; m < 2; ++m) {
        #pragma unroll
        for (int j = 0; j < 4; ++j) {
          const float v = acc[m][n][j] + bv;
          if (WW) {
            if (rga[m][j] < ne)
              Wout[(size_t)rga[m][j] * 4096 + col] = __float2bfloat16(v);
          }
          msg[m][n & 3][j] = fmaf(hsc[m][j][n >> 2], v, msg[m][n & 3][j]);
        }
      }
    }
  }

  #pragma unroll
  for (int m = 0; m < 2; ++m) {
    #pragma unroll
    for (int j = 0; j < 4; ++j) {
      if (val[m][j]) {
        float* ag = agg + (size_t)dstr[m][j] * 64;
        #pragma unroll
        for (int na = 0; na < 4; ++na)
          atomicAdd(ag + (na << 4) + lo, msg[m][na][j]);
      }
    }
  }
}

// wt[n*K + k] = bf16(w[k*N + n])  (transpose + cast)
__global__ void convert_t(const float* __restrict__ w, bf16_t* __restrict__ wt,
                          int K, int N) {
  int idx = blockIdx.x * 256 + threadIdx.x;
  if (idx >= K * N) return;
  int n = idx / K, k = idx - n * K;
  wt[idx] = __float2bfloat16(w[(size_t)k * N + n]);
}

__global__ void fc1_kernel(const float* __restrict__ x, const float* __restrict__ w,
                           const float* __restrict__ b, float* __restrict__ h) {
  int idx = blockIdx.x * 256 + threadIdx.x;
  if (idx >= NN * 64) return;
  int n = idx >> 6, j = idx & 63;
  h[idx] = fmaf(x[n], w[j], b[j]);
}

__global__ void deg_kernel(const int* __restrict__ ei, float* __restrict__ deg) {
  int e = blockIdx.x * 256 + threadIdx.x;
  if (e < EE) {
    unsigned d = (unsigned)ei[EE + e];
    if (d < NN) atomicAdd(&deg[d], 1.0f);
  }
}

// e1[el][0:256] = relu(attr[e0+el] @ k1_w + k1_b), zeros for rows >= ne
__global__ void k1_kernel(const float* __restrict__ attr, const float* __restrict__ w,
                          const float* __restrict__ b, bf16_t* __restrict__ e1,
                          int e0, int ne) {
  const int el = blockIdx.x;
  const int j = threadIdx.x;
  __shared__ float a[6];
  if (el < ne && j < 6) a[j] = attr[(size_t)(e0 + el) * 6 + j];
  __syncthreads();
  float v = 0.0f;
  if (el < ne) {
    v = b[j];
    #pragma unroll
    for (int i = 0; i < 6; ++i) v = fmaf(a[i], w[i * 256 + j], v);
    v = fmaxf(v, 0.0f);
  }
  e1[(size_t)el * 256 + j] = __float2bfloat16(v);
}

// per-edge matvec from cached W (bf16): msg[o] = sum_i h[src][i]*W[el][i*64+o]
__global__ __launch_bounds__(256)
void msg_kernel(const float* __restrict__ h, const bf16_t* __restrict__ W,
                const int* __restrict__ ei, float* __restrict__ agg,
                int e0, int ne) {
  const int el = blockIdx.x * 4 + (threadIdx.x >> 6);
  if (el >= ne) return;
  const int e = e0 + el;
  const int lane = threadIdx.x & 63;
  const int g = lane >> 4, c = lane & 15;
  const unsigned src = (unsigned)ei[e], dst = (unsigned)ei[EE + e];
  if (src >= NN || dst >= NN) return;
  const float hv = h[src * 64 + lane];
  const unsigned short* We = (const unsigned short*)(W + (size_t)el * 4096);
  float a0 = 0, a1 = 0, a2 = 0, a3 = 0;
  #pragma unroll
  for (int i0 = 0; i0 < 64; i0 += 4) {
    const int i = i0 + g;
    const float hs = __shfl(hv, i);
    ushort4 wv = *(const ushort4*)(We + i * 64 + c * 4);
    a0 = fmaf(hs, bf2f(wv.x), a0);
    a1 = fmaf(hs, bf2f(wv.y), a1);
    a2 = fmaf(hs, bf2f(wv.z), a2);
    a3 = fmaf(hs, bf2f(wv.w), a3);
  }
  a0 += __shfl_xor(a0, 16); a0 += __shfl_xor(a0, 32);
  a1 += __shfl_xor(a1, 16); a1 += __shfl_xor(a1, 32);
  a2 += __shfl_xor(a2, 16); a2 += __shfl_xor(a2, 32);
  a3 += __shfl_xor(a3, 16); a3 += __shfl_xor(a3, 32);
  if (g == 0) {
    float* ag = agg + (size_t)dst * 64 + c * 4;
    atomicAdd(ag + 0, a0);
    atomicAdd(ag + 1, a1);
    atomicAdd(ag + 2, a2);
    atomicAdd(ag + 3, a3);
  }
}

// h_new = relu(agg/deg + h @ root + gcn_b)
__global__ __launch_bounds__(256)
void update_kernel(const float* __restrict__ h, const float* __restrict__ agg,
                   const float* __restrict__ deg, const float* __restrict__ root,
                   const float* __restrict__ gb, float* __restrict__ hn) {
  const int n = blockIdx.x * 4 + (threadIdx.x >> 6);
  if (n >= NN) return;
  const int lane = threadIdx.x & 63;
  const float hv = h[n * 64 + lane];
  float acc = 0.0f;
  #pragma unroll
  for (int i = 0; i < 64; ++i)
    acc = fmaf(__shfl(hv, i), root[i * 64 + lane], acc);
  const float d = fmaxf(deg[n], 1.0f);
  const float v = agg[n * 64 + lane] / d + acc + gb[lane];
  hn[n * 64 + lane] = fmaxf(v, 0.0f);
}

__global__ __launch_bounds__(256)
void fc2_kernel(const float* __restrict__ h, const float* __restrict__ w,
                const float* __restrict__ b, float* __restrict__ out) {
  const int n = blockIdx.x * 4 + (threadIdx.x >> 6);
  if (n >= NN) return;
  const int lane = threadIdx.x & 63;
  float v = h[n * 64 + lane] * w[lane];
  #pragma unroll
  for (int off = 32; off > 0; off >>= 1) v += __shfl_xor(v, off);
  if (lane == 0) out[n] = v + b[0];
}

extern "C" void kernel_launch(void* const* d_in, const int* in_sizes, int n_in,
                              void* d_out, int out_size, void* d_ws, size_t ws_size,
                              hipStream_t stream) {
  const float* x     = (const float*)d_in[0];
  const int*   ei    = (const int*)d_in[1];
  const float* attr  = (const float*)d_in[2];
  const float* fc1_w = (const float*)d_in[3];
  const float* fc1_b = (const float*)d_in[4];
  const float* k1_w  = (const float*)d_in[5];
  const float* k1_b  = (const float*)d_in[6];
  const float* k2_w  = (const float*)d_in[7];
  const float* k2_b  = (const float*)d_in[8];
  const float* k3_w  = (const float*)d_in[9];
  const float* k3_b  = (const float*)d_in[10];
  const float* root  = (const float*)d_in[11];
  const float* gcn_b = (const float*)d_in[12];
  const float* fc2_w = (const float*)d_in[13];
  const float* fc2_b = (const float*)d_in[14];
  float* out = (float*)d_out;
  (void)in_sizes; (void)n_in; (void)out_size;

  char* ws = (char*)d_ws;
  size_t off = 0;
  auto take = [&](size_t bytes) -> char* {
    char* p = ws + off;
    off += (bytes + 255) & ~(size_t)255;
    return p;
  };
  // fixed small buffers (~12.2 MB)
  bf16_t* k2wt = (bf16_t*)take((size_t)512 * 256 * 2);
  bf16_t* k3wt = (bf16_t*)take((size_t)4096 * 512 * 2);
  float*  hA   = (float*)take((size_t)NN * 64 * 4);
  float*  hB   = (float*)take((size_t)NN * 64 * 4);
  float*  agg  = (float*)take((size_t)NN * 64 * 4);
  float*  deg  = (float*)take((size_t)NN * 4);

  // e2 cached for all edges (51.4 MB); W cache gets the rest; e1 aliased into Wcache
  bf16_t* e2full = (bf16_t*)take((size_t)MPAD * 512 * 2);
  size_t rem = (ws_size > off + 1024) ? ws_size - off - 1024 : 0;
  int Nc = (int)((rem / 8192) / 128) * 128;   // cached edges (mult of 128)
  if (Nc > 49920) Nc = 49920;
  if (Nc < 0) Nc = 0;
  size_t e1B = (size_t)MPAD * 256 * 2;        // 25.7 MB
  size_t regionB = (size_t)Nc * 8192;
  if (regionB < e1B) regionB = e1B;
  char* region = take(regionB);
  bf16_t* Wcache = (bf16_t*)region;
  bf16_t* e1 = (bf16_t*)region;               // dead after k2; overwritten by Wcache fill

  const int Te = EE - Nc;                     // tail (recomputed fused each layer)
  const int Mt = (Te + 127) & ~127;

  // weight transposes + casts
  convert_t<<<(512 * 256 + 255) / 256, 256, 0, stream>>>(k2_w, k2wt, 256, 512);
  convert_t<<<(4096 * 512 + 255) / 256, 256, 0, stream>>>(k3_w, k3wt, 512, 4096);

  // h0 = x @ fc1_w + fc1_b
  fc1_kernel<<<(NN * 64 + 255) / 256, 256, 0, stream>>>(x, fc1_w, fc1_b, hA);

  // in-degree
  hipMemsetAsync(deg, 0, NN * 4, stream);
  deg_kernel<<<(EE + 255) / 256, 256, 0, stream>>>(ei, deg);

  // edge MLP front: e1 (full) then e2 (full), one dispatch each
  k1_kernel<<<MPAD, 256, 0, stream>>>(attr, k1_w, k1_b, e1, 0, EE);
  gemm_bt<true><<<(MPAD >> 7) * 4, 256, 0, stream>>>(e1, k2wt, k2_b, e2full, 512, 256);

  float* hc = hA;
  float* hn = hB;
  for (int l = 0; l < 3; ++l) {
    hipMemsetAsync(agg, 0, (size_t)NN * 64 * 4, stream);
    if (l == 0) {
      if (Nc > 0)  // fill W cache AND do layer-0 msg for cached edges
        k3msg<true><<<(Nc >> 7) * 4, 256, 0, stream>>>(
            e2full, k3wt, k3_b, hc, ei, agg, Wcache, 0, Nc);
    } else if (Nc > 0) {
      msg_kernel<<<(Nc + 3) / 4, 256, 0, stream>>>(hc, Wcache, ei, agg, 0, Nc);
    }
    if (Te > 0)  // tail: fused recompute + msg, no W materialization
      k3msg<false><<<(Mt >> 7) * 4, 256, 0, stream>>>(
          e2full + (size_t)Nc * 512, k3wt, k3_b, hc, ei, agg, nullptr, Nc, Te);
    update_kernel<<<(NN + 3) / 4, 256, 0, stream>>>(hc, agg, deg, root, gcn_b, hn);
    float* tmp = hc; hc = hn; hn = tmp;
  }

  fc2_kernel<<<(NN + 3) / 4, 256, 0, stream>>>(hc, fc2_w, fc2_b, out);
}

// Round 6
// 838.981 us; speedup vs baseline: 1.7787x; 1.0779x over previous
//
#include <hip/hip_runtime.h>
#include <hip/hip_bf16.h>
#include <stdint.h>

#define NN 10000
#define EE 50000
#define MPAD 50176  // EE padded to multiple of 128

typedef __hip_bfloat16 bf16_t;
typedef __attribute__((ext_vector_type(8))) short bf16x8;
typedef __attribute__((ext_vector_type(4))) float f32x4;

__device__ __forceinline__ float bf2f(unsigned short u) {
  union { unsigned int i; float f; } v; v.i = ((unsigned int)u) << 16; return v.f;
}

__device__ __forceinline__ void async_load16(const void* g, void* lds) {
  __builtin_amdgcn_global_load_lds((const __attribute__((address_space(1))) uint32_t*)g,
                                   (__attribute__((address_space(3))) uint32_t*)lds,
                                   16, 0, 0);
}

#define MFMA16(a, b, c) __builtin_amdgcn_mfma_f32_16x16x32_bf16(a, b, c, 0, 0, 0)

// C[M][N] = act(A[M][K] @ Bt[N][K]^T + bias[N]); bf16 row-major, M,N mult 128, K mult 64.
// Proven r2 structure: 944 TF, MfmaUtil 42%, 0 bank conflicts. DO NOT TOUCH without A/B.
template <bool RELU>
__global__ __launch_bounds__(256, 2)
void gemm_bt(const bf16_t* __restrict__ A, const bf16_t* __restrict__ Bt,
             const float* __restrict__ bias, bf16_t* __restrict__ C,
             int N, int K) {
  __shared__ __align__(16) bf16_t As[128 * 64];
  __shared__ __align__(16) bf16_t Bs[128 * 64];

  const int t = threadIdx.x;
  const int lane = t & 63;
  const int wave = t >> 6;
  const int nt = N >> 7;
  const int bm = blockIdx.x / nt;
  const int bn = blockIdx.x % nt;
  const size_t aRowBase = (size_t)bm << 7;
  const size_t bRowBase = (size_t)bn << 7;

  const int wrBase = (wave >> 1) << 6;
  const int wcBase = (wave & 1) << 6;
  const int lo = lane & 15;
  const int hi = lane >> 4;

  f32x4 acc[4][4] = {};

  const int stg_r = t >> 3;
  const int stg_s = t & 7;
  char* AsB = (char*)As;
  char* BsB = (char*)Bs;

  const int nkt = K >> 6;
  for (int kt = 0; kt < nkt; ++kt) {
    __syncthreads();
    #pragma unroll
    for (int it = 0; it < 4; ++it) {
      const int r = (it << 5) + stg_r;
      const int ls = (stg_s ^ (r & 7)) << 3;
      async_load16(A + (aRowBase + r) * K + (kt << 6) + ls,
                   AsB + (it << 12) + (wave << 10));
      async_load16(Bt + (bRowBase + r) * K + (kt << 6) + ls,
                   BsB + (it << 12) + (wave << 10));
    }
    __syncthreads();
    #pragma unroll
    for (int ks = 0; ks < 2; ++ks) {
      bf16x8 af[4], bfr[4];
      #pragma unroll
      for (int m = 0; m < 4; ++m) {
        const int row = wrBase + (m << 4) + lo;
        const int ps = ((ks << 2) + hi) ^ (row & 7);
        af[m] = *(const bf16x8*)(AsB + (row << 7) + (ps << 4));
      }
      #pragma unroll
      for (int n = 0; n < 4; ++n) {
        const int row = wcBase + (n << 4) + lo;
        const int ps = ((ks << 2) + hi) ^ (row & 7);
        bfr[n] = *(const bf16x8*)(BsB + (row << 7) + (ps << 4));
      }
      #pragma unroll
      for (int m = 0; m < 4; ++m)
        #pragma unroll
        for (int n = 0; n < 4; ++n)
          acc[m][n] = MFMA16(af[m], bfr[n], acc[m][n]);
    }
  }

  #pragma unroll
  for (int m = 0; m < 4; ++m) {
    #pragma unroll
    for (int n = 0; n < 4; ++n) {
      const int col = (bn << 7) + wcBase + (n << 4) + lo;
      const float bv = bias[col];
      #pragma unroll
      for (int j = 0; j < 4; ++j) {
        const int row = (bm << 7) + wrBase + (m << 4) + (hi << 2) + j;
        float v = acc[m][n][j] + bv;
        if (RELU) v = fmaxf(v, 0.0f);
        C[(size_t)row * N + col] = __float2bfloat16(v);
      }
    }
  }
}

// Fused k3 GEMM + per-edge matvec + atomic scatter, A-tile LDS-resident.
// A = e2 rows (dispatch-local), Bt = k3wt [4096][512], b3 = k3_b.
// Block: 128 edges. K in 2 passes of 256 (A-LDS 64KB restaged per pass);
// per pass: 16 col-tiles of 256 (bi2), B double-buffered (2x32KB), one
// barrier per (bi2,kt) step, stage-next-before-compute.
// 8 waves: wr=w>>2 (64-row group), wc=w&3; wave n-frags at cols nf*64+wc*16
// so each wave owns the complete i-sum for its (row, o=wc*16+lo) outputs.
__global__ __launch_bounds__(512, 1)
void k3msg2(const bf16_t* __restrict__ A, const bf16_t* __restrict__ Bt,
            const float* __restrict__ b3, const float* __restrict__ h,
            const int* __restrict__ ei, float* __restrict__ agg,
            int e0, int ne) {
  __shared__ __align__(16) char AL[65536];     // [kt4][row128][slot8]*16B
  __shared__ __align__(16) char BL[2][32768];  // [col256][slot8]*16B

  const int t = threadIdx.x, lane = t & 63, w = t >> 6;
  const int wr = w >> 2, wc = w & 3;
  const int lo = lane & 15, hi = lane >> 4;
  const int aRow0 = blockIdx.x << 7;
  const int o = (wc << 4) + lo;

  // per-lane edge rows r(m,j) = wr*64 + m*16 + hi*4 + j
  int srcr[4][4], dstr[4][4];
  bool val[4][4];
  #pragma unroll
  for (int m = 0; m < 4; ++m)
    #pragma unroll
    for (int j = 0; j < 4; ++j) {
      const int rg = aRow0 + (wr << 6) + (m << 4) + (hi << 2) + j;
      bool v = rg < ne;
      unsigned sv = 0, dv = 0;
      if (v) {
        sv = (unsigned)ei[e0 + rg];
        dv = (unsigned)ei[EE + e0 + rg];
        if (sv >= NN || dv >= NN) v = false;
      }
      srcr[m][j] = (int)sv; dstr[m][j] = (int)dv; val[m][j] = v;
    }

  const int str = t >> 3;  // 0..63
  const int sts = t & 7;

  float msg[4][4] = {};  // [m][j], o fixed per lane

  int buf = 0;
  for (int kp = 0; kp < 2; ++kp) {
    // stage A half (read-only for this pass) + first B tile
    #pragma unroll
    for (int kt = 0; kt < 4; ++kt)
      #pragma unroll
      for (int q = 0; q < 2; ++q) {
        const int r = str + (q << 6);
        const int ls = ((sts ^ (r & 7)) << 3) + (kp << 8) + (kt << 6);
        async_load16(A + (size_t)(aRow0 + r) * 512 + ls,
                     AL + (kt << 14) + (((q << 6) + (w << 3)) << 7));
      }
    {
      #pragma unroll
      for (int q = 0; q < 4; ++q) {
        const int c = str + (q << 6);
        const int ls = ((sts ^ (c & 7)) << 3) + (kp << 8);
        async_load16(Bt + (size_t)c * 512 + ls,
                     BL[buf] + (((q << 6) + (w << 3)) << 7));
      }
    }
    asm volatile("s_waitcnt vmcnt(0)" ::: "memory");
    __syncthreads();
    asm volatile("" ::: "memory");

    for (int bi2 = 0; bi2 < 16; ++bi2) {
      f32x4 acc[4][4] = {};  // [m][nf]
      for (int kt = 0; kt < 4; ++kt) {
        // prefetch next step's B into buf^1 (flies during compute)
        const int nb2 = (kt < 3) ? bi2 : bi2 + 1;
        const int nkt = (kt < 3) ? kt + 1 : 0;
        if (nb2 < 16) {
          #pragma unroll
          for (int q = 0; q < 4; ++q) {
            const int c = str + (q << 6);
            const int ls = ((sts ^ (c & 7)) << 3) + (kp << 8) + (nkt << 6);
            async_load16(Bt + (size_t)((nb2 << 8) + c) * 512 + ls,
                         BL[buf ^ 1] + (((q << 6) + (w << 3)) << 7));
          }
        }
        // compute current
        #pragma unroll
        for (int ks = 0; ks < 2; ++ks) {
          bf16x8 af[4], bfv[4];
          #pragma unroll
          for (int m = 0; m < 4; ++m) {
            const int row = (wr << 6) + (m << 4) + lo;
            af[m] = *(const bf16x8*)(AL + (kt << 14) + (row << 7) +
                                     ((((ks << 2) + hi) ^ (row & 7)) << 4));
          }
          #pragma unroll
          for (int nf = 0; nf < 4; ++nf) {
            const int col = (nf << 6) + (wc << 4) + lo;
            bfv[nf] = *(const bf16x8*)(BL[buf] + (col << 7) +
                                       ((((ks << 2) + hi) ^ (col & 7)) << 4));
          }
          #pragma unroll
          for (int m = 0; m < 4; ++m)
            #pragma unroll
            for (int nf = 0; nf < 4; ++nf)
              acc[m][nf] = MFMA16(af[m], bfv[nf], acc[m][nf]);
        }
        if (kt == 3) {
          // fold partial-K C-tile into msg (linear => K-split valid; bias on kp0)
          float bv[4];
          #pragma unroll
          for (int nf = 0; nf < 4; ++nf)
            bv[nf] = (kp == 0) ? b3[(bi2 << 8) + (nf << 6) + o] : 0.0f;
          #pragma unroll
          for (int m = 0; m < 4; ++m)
            #pragma unroll
            for (int j = 0; j < 4; ++j) {
              float4 hv = val[m][j]
                  ? *(const float4*)(h + ((size_t)srcr[m][j] << 6) + (bi2 << 2))
                  : make_float4(0.0f, 0.0f, 0.0f, 0.0f);
              float s = msg[m][j];
              s = fmaf(hv.x, acc[m][0][j] + bv[0], s);
              s = fmaf(hv.y, acc[m][1][j] + bv[1], s);
              s = fmaf(hv.z, acc[m][2][j] + bv[2], s);
              s = fmaf(hv.w, acc[m][3][j] + bv[3], s);
              msg[m][j] = s;
            }
        }
        asm volatile("s_waitcnt vmcnt(0)" ::: "memory");
        __syncthreads();
        asm volatile("" ::: "memory");
        buf ^= 1;
      }
    }
  }

  #pragma unroll
  for (int m = 0; m < 4; ++m)
    #pragma unroll
    for (int j = 0; j < 4; ++j)
      if (val[m][j])
        atomicAdd(agg + ((size_t)dstr[m][j] << 6) + o, msg[m][j]);
}

// wt[n*K + k] = bf16(w[k*N + n])  (transpose + cast)
__global__ void convert_t(const float* __restrict__ w, bf16_t* __restrict__ wt,
                          int K, int N) {
  int idx = blockIdx.x * 256 + threadIdx.x;
  if (idx >= K * N) return;
  int n = idx / K, k = idx - n * K;
  wt[idx] = __float2bfloat16(w[(size_t)k * N + n]);
}

__global__ void fc1_kernel(const float* __restrict__ x, const float* __restrict__ w,
                           const float* __restrict__ b, float* __restrict__ h) {
  int idx = blockIdx.x * 256 + threadIdx.x;
  if (idx >= NN * 64) return;
  int n = idx >> 6, j = idx & 63;
  h[idx] = fmaf(x[n], w[j], b[j]);
}

__global__ void deg_kernel(const int* __restrict__ ei, float* __restrict__ deg) {
  int e = blockIdx.x * 256 + threadIdx.x;
  if (e < EE) {
    unsigned d = (unsigned)ei[EE + e];
    if (d < NN) atomicAdd(&deg[d], 1.0f);
  }
}

// e1[el][0:256] = relu(attr[e0+el] @ k1_w + k1_b), zeros for rows >= ne
__global__ void k1_kernel(const float* __restrict__ attr, const float* __restrict__ w,
                          const float* __restrict__ b, bf16_t* __restrict__ e1,
                          int e0, int ne) {
  const int el = blockIdx.x;
  const int j = threadIdx.x;
  __shared__ float a[6];
  if (el < ne && j < 6) a[j] = attr[(size_t)(e0 + el) * 6 + j];
  __syncthreads();
  float v = 0.0f;
  if (el < ne) {
    v = b[j];
    #pragma unroll
    for (int i = 0; i < 6; ++i) v = fmaf(a[i], w[i * 256 + j], v);
    v = fmaxf(v, 0.0f);
  }
  e1[(size_t)el * 256 + j] = __float2bfloat16(v);
}

// per-edge matvec from cached W (bf16): msg[o] = sum_i h[src][i]*W[el][i*64+o]
__global__ __launch_bounds__(256)
void msg_kernel(const float* __restrict__ h, const bf16_t* __restrict__ W,
                const int* __restrict__ ei, float* __restrict__ agg,
                int e0, int ne) {
  const int el = blockIdx.x * 4 + (threadIdx.x >> 6);
  if (el >= ne) return;
  const int e = e0 + el;
  const int lane = threadIdx.x & 63;
  const int g = lane >> 4, c = lane & 15;
  const unsigned src = (unsigned)ei[e], dst = (unsigned)ei[EE + e];
  if (src >= NN || dst >= NN) return;
  const float hv = h[src * 64 + lane];
  const unsigned short* We = (const unsigned short*)(W + (size_t)el * 4096);
  float a0 = 0, a1 = 0, a2 = 0, a3 = 0;
  #pragma unroll
  for (int i0 = 0; i0 < 64; i0 += 4) {
    const int i = i0 + g;
    const float hs = __shfl(hv, i);
    ushort4 wv = *(const ushort4*)(We + i * 64 + c * 4);
    a0 = fmaf(hs, bf2f(wv.x), a0);
    a1 = fmaf(hs, bf2f(wv.y), a1);
    a2 = fmaf(hs, bf2f(wv.z), a2);
    a3 = fmaf(hs, bf2f(wv.w), a3);
  }
  a0 += __shfl_xor(a0, 16); a0 += __shfl_xor(a0, 32);
  a1 += __shfl_xor(a1, 16); a1 += __shfl_xor(a1, 32);
  a2 += __shfl_xor(a2, 16); a2 += __shfl_xor(a2, 32);
  a3 += __shfl_xor(a3, 16); a3 += __shfl_xor(a3, 32);
  if (g == 0) {
    float* ag = agg + (size_t)dst * 64 + c * 4;
    atomicAdd(ag + 0, a0);
    atomicAdd(ag + 1, a1);
    atomicAdd(ag + 2, a2);
    atomicAdd(ag + 3, a3);
  }
}

// h_new = relu(agg/deg + h @ root + gcn_b)
__global__ __launch_bounds__(256)
void update_kernel(const float* __restrict__ h, const float* __restrict__ agg,
                   const float* __restrict__ deg, const float* __restrict__ root,
                   const float* __restrict__ gb, float* __restrict__ hn) {
  const int n = blockIdx.x * 4 + (threadIdx.x >> 6);
  if (n >= NN) return;
  const int lane = threadIdx.x & 63;
  const float hv = h[n * 64 + lane];
  float acc = 0.0f;
  #pragma unroll
  for (int i = 0; i < 64; ++i)
    acc = fmaf(__shfl(hv, i), root[i * 64 + lane], acc);
  const float d = fmaxf(deg[n], 1.0f);
  const float v = agg[n * 64 + lane] / d + acc + gb[lane];
  hn[n * 64 + lane] = fmaxf(v, 0.0f);
}

__global__ __launch_bounds__(256)
void fc2_kernel(const float* __restrict__ h, const float* __restrict__ w,
                const float* __restrict__ b, float* __restrict__ out) {
  const int n = blockIdx.x * 4 + (threadIdx.x >> 6);
  if (n >= NN) return;
  const int lane = threadIdx.x & 63;
  float v = h[n * 64 + lane] * w[lane];
  #pragma unroll
  for (int off = 32; off > 0; off >>= 1) v += __shfl_xor(v, off);
  if (lane == 0) out[n] = v + b[0];
}

extern "C" void kernel_launch(void* const* d_in, const int* in_sizes, int n_in,
                              void* d_out, int out_size, void* d_ws, size_t ws_size,
                              hipStream_t stream) {
  const float* x     = (const float*)d_in[0];
  const int*   ei    = (const int*)d_in[1];
  const float* attr  = (const float*)d_in[2];
  const float* fc1_w = (const float*)d_in[3];
  const float* fc1_b = (const float*)d_in[4];
  const float* k1_w  = (const float*)d_in[5];
  const float* k1_b  = (const float*)d_in[6];
  const float* k2_w  = (const float*)d_in[7];
  const float* k2_b  = (const float*)d_in[8];
  const float* k3_w  = (const float*)d_in[9];
  const float* k3_b  = (const float*)d_in[10];
  const float* root  = (const float*)d_in[11];
  const float* gcn_b = (const float*)d_in[12];
  const float* fc2_w = (const float*)d_in[13];
  const float* fc2_b = (const float*)d_in[14];
  float* out = (float*)d_out;
  (void)in_sizes; (void)n_in; (void)out_size;

  char* ws = (char*)d_ws;
  size_t off = 0;
  auto take = [&](size_t bytes) -> char* {
    char* p = ws + off;
    off += (bytes + 255) & ~(size_t)255;
    return p;
  };
  // fixed small buffers (~12.2 MB)
  bf16_t* k2wt = (bf16_t*)take((size_t)512 * 256 * 2);
  bf16_t* k3wt = (bf16_t*)take((size_t)4096 * 512 * 2);
  float*  hA   = (float*)take((size_t)NN * 64 * 4);
  float*  hB   = (float*)take((size_t)NN * 64 * 4);
  float*  agg  = (float*)take((size_t)NN * 64 * 4);
  float*  deg  = (float*)take((size_t)NN * 4);

  // e2 for all edges (51.4 MB); remaining region = e1 (transient) then Wcache
  bf16_t* e2full = (bf16_t*)take((size_t)MPAD * 512 * 2);
  size_t rem = (ws_size > off + 1024) ? ws_size - off - 1024 : 0;
  int Nc = (int)((rem / 8192) / 128) * 128;  // cached edges, mult of 128
  if (Nc > MPAD - 128) Nc = MPAD - 128;
  if (Nc < 0) Nc = 0;
  size_t e1B = (size_t)MPAD * 256 * 2;  // 25.7 MB
  size_t regionB = (size_t)Nc * 8192;
  if (regionB < e1B) regionB = e1B;
  char* region = take(regionB);
  bf16_t* Wcache = (bf16_t*)region;
  bf16_t* e1 = (bf16_t*)region;  // dead after k2; overwritten by Wcache fill

  const int Te = EE - Nc;              // tail edges (fused-recomputed per layer)
  const int Mt = (Te + 127) & ~127;

  // weight transposes + casts
  convert_t<<<(512 * 256 + 255) / 256, 256, 0, stream>>>(k2_w, k2wt, 256, 512);
  convert_t<<<(4096 * 512 + 255) / 256, 256, 0, stream>>>(k3_w, k3wt, 512, 4096);

  // h0 = x @ fc1_w + fc1_b
  fc1_kernel<<<(NN * 64 + 255) / 256, 256, 0, stream>>>(x, fc1_w, fc1_b, hA);

  // in-degree
  hipMemsetAsync(deg, 0, NN * 4, stream);
  deg_kernel<<<(EE + 255) / 256, 256, 0, stream>>>(ei, deg);

  // edge MLP front (full): k1 -> e1, k2 -> e2full
  k1_kernel<<<MPAD, 256, 0, stream>>>(attr, k1_w, k1_b, e1, 0, EE);
  gemm_bt<true><<<(MPAD >> 7) * 4, 256, 0, stream>>>(e1, k2wt, k2_b, e2full, 512, 256);

  // W cache fill (h-independent, once): proven 944-TF GEMM
  if (Nc > 0)
    gemm_bt<false><<<(Nc >> 7) * 32, 256, 0, stream>>>(e2full, k3wt, k3_b, Wcache, 4096, 512);

  float* hc = hA;
  float* hn = hB;
  for (int l = 0; l < 3; ++l) {
    hipMemsetAsync(agg, 0, (size_t)NN * 64 * 4, stream);
    if (Nc > 0)
      msg_kernel<<<(Nc + 3) / 4, 256, 0, stream>>>(hc, Wcache, ei, agg, 0, Nc);
    if (Te > 0)
      k3msg2<<<Mt >> 7, 512, 0, stream>>>(e2full + (size_t)Nc * 512, k3wt, k3_b,
                                          hc, ei, agg, Nc, Te);
    update_kernel<<<(NN + 3) / 4, 256, 0, stream>>>(hc, agg, deg, root, gcn_b, hn);
    float* tmp = hc; hc = hn; hn = tmp;
  }

  fc2_kernel<<<(NN + 3) / 4, 256, 0, stream>>>(hc, fc2_w, fc2_b, out);
}